// Round 3
// baseline (607.003 us; speedup 1.0000x reference)
//
#include <hip/hip_runtime.h>
#include <stdint.h>
#include <math.h>

// ---------------------------------------------------------------------------
// GraphDistillOperatorWithEdgeWeight, N=8192, F=256, OUT=256
//
//   E_ij = exp(5*adj_ij), E_ii = 0 ; s_i = sum_j E_ij ; a = E/s
//   agg = a@feat ; kagg = a@key
//   out1 = tanh(Xcat @ W1 + c1),  Xcat=[feat|agg],  W1=[[W_o],[0]] - W_d@W_o
//   out2 = tanh(Kcat @ W2 + c2),  Kcat=[key|kagg],  W2=[[W_ao],[W_a@W_ao]]
//
// exp_gemm v3: adj staged via global_load_lds (un-sinkable DMA) into a 3-slot
// LDS ring, prefetched 2 chunks ahead; barrier waits vmcnt(2) (never drains
// the in-flight DMA). LDS f32 -> expf -> bf16 sA (padded, dbuf) -> MFMA32.
// grid 512 (64 M x 2 Nhalf x 4 Ksplit), block 512 (8 waves), 2 blocks/CU.
// ---------------------------------------------------------------------------

typedef __attribute__((ext_vector_type(4)))  short bf16x4_t;
typedef __attribute__((ext_vector_type(8)))  short bf16x8_t;
typedef __attribute__((ext_vector_type(4)))  float f32x4_t;
typedef __attribute__((ext_vector_type(16))) float f32x16_t;

#define MFMA32(A, B, C) __builtin_amdgcn_mfma_f32_32x32x16_bf16(A, B, C, 0, 0, 0)
#define MFMA16(A, B, C) __builtin_amdgcn_mfma_f32_16x16x32_bf16(A, B, C, 0, 0, 0)

__device__ __forceinline__ unsigned short f2bf(float x) {
    union { float f; unsigned u; } c; c.f = x;
    unsigned u = c.u;
    return (unsigned short)((u + 0x7fffu + ((u >> 16) & 1u)) >> 16);  // RNE
}
__device__ __forceinline__ unsigned pack2bf(float a, float b) {
    return (unsigned)f2bf(a) | ((unsigned)f2bf(b) << 16);
}
__device__ __forceinline__ float bflo(unsigned u) {
    union { unsigned u; float f; } c; c.u = u << 16; return c.f;
}
__device__ __forceinline__ float bfhi(unsigned u) {
    union { unsigned u; float f; } c; c.u = u & 0xffff0000u; return c.f;
}

// global -> LDS async DMA, 16 B per lane. lds ptr must be wave-uniform base.
__device__ __forceinline__ void dma16(const float* g, float* lds_base) {
    __builtin_amdgcn_global_load_lds(
        (const __attribute__((address_space(1))) unsigned*)g,
        (__attribute__((address_space(3))) unsigned*)lds_base, 16, 0, 0);
}

// ---------------------------------------------------------------------------
// 32x32 tiled transpose: dst[c][r] = bf16(src[r][c]). grid=(R/32, C/32).
// ---------------------------------------------------------------------------
__global__ __launch_bounds__(256) void transpose_f32_bf16(
    const float* __restrict__ src, unsigned short* __restrict__ dst, int R, int C)
{
    __shared__ float tile[32][33];
    const int x  = threadIdx.x & 31;
    const int y4 = (threadIdx.x >> 5) * 4;
    const int r0 = blockIdx.x * 32;
    const int c0 = blockIdx.y * 32;
#pragma unroll
    for (int i = 0; i < 4; ++i)
        tile[y4 + i][x] = src[(size_t)(r0 + y4 + i) * C + c0 + x];
    __syncthreads();
#pragma unroll
    for (int i = 0; i < 4; ++i)
        dst[(size_t)(c0 + y4 + i) * R + r0 + x] = f2bf(tile[x][y4 + i]);
}

// dst row-major uint rows of 256 (=512 bf16 cols), fill cols 0..255. grid=4096.
__global__ __launch_bounds__(256) void pack_half(
    const float* __restrict__ src, unsigned* __restrict__ dst)
{
    const int idx = blockIdx.x * 256 + threadIdx.x;
    const int row = idx >> 7, cp = idx & 127;
    float2 v = *(const float2*)(src + (size_t)row * 256 + cp * 2);
    dst[(size_t)row * 256 + cp] = pack2bf(v.x, v.y);
}

// ---------------------------------------------------------------------------
// Weight composition (see header). grid = 512, block = 256.
// ---------------------------------------------------------------------------
__global__ __launch_bounds__(256) void compose1(
    const float* __restrict__ W_d, const float* __restrict__ W_o,
    unsigned short* __restrict__ W1t)
{
    __shared__ float wrow[256];
    const int k = blockIdx.x, t = threadIdx.x;
    wrow[t] = W_d[(size_t)k * 256 + t];
    __syncthreads();
    float acc = 0.f;
#pragma unroll 8
    for (int m = 0; m < 256; ++m) acc = fmaf(wrow[m], W_o[(size_t)m * 256 + t], acc);
    const float v = (k < 256 ? W_o[(size_t)k * 256 + t] : 0.f) - acc;
    W1t[(size_t)t * 512 + k] = f2bf(v);
}

__global__ __launch_bounds__(256) void compose2(
    const float* __restrict__ W_a, const float* __restrict__ W_ao,
    unsigned short* __restrict__ W2t)
{
    __shared__ float wrow[256];
    const int k = blockIdx.x, t = threadIdx.x;
    float v;
    if (k < 256) {
        v = W_ao[(size_t)k * 256 + t];
    } else {
        wrow[t] = W_a[(size_t)(k - 256) * 256 + t];
        __syncthreads();
        float acc = 0.f;
#pragma unroll 8
        for (int m = 0; m < 256; ++m) acc = fmaf(wrow[m], W_ao[(size_t)m * 256 + t], acc);
        v = acc;
    }
    W2t[(size_t)t * 512 + k] = f2bf(v);
}

__global__ __launch_bounds__(256) void biasC(
    const float* __restrict__ b_d, const float* __restrict__ b_o,
    const float* __restrict__ b_a, const float* __restrict__ b_ao,
    const float* __restrict__ W_o, const float* __restrict__ W_ao,
    float* __restrict__ c1, float* __restrict__ c2)
{
    const int t = threadIdx.x;
    float a1 = 0.f, a2 = 0.f;
#pragma unroll 8
    for (int m = 0; m < 256; ++m) {
        a1 = fmaf(b_d[m], W_o [(size_t)m * 256 + t], a1);
        a2 = fmaf(b_a[m], W_ao[(size_t)m * 256 + t], a2);
    }
    c1[t] = b_o[t] - a1;
    c2[t] = b_ao[t] + a2;
}

// ---------------------------------------------------------------------------
// exp_gemm v3.
// Block: tile 128 rows x 256 cols, K-slice 2048, chunks of BK=32 (64 chunks).
// LDS: raw adj ring [3][128x32 f32] (48 KB) + sA bf16 dbuf [2][128x36] (18 KB).
// ---------------------------------------------------------------------------
#define NCHV3 64
#define SASTR 36   // sA row stride in shorts (72 B -> 2-way bank max)

__global__ __launch_bounds__(512, 4) void exp_gemm(
    const float* __restrict__ adj, const unsigned short* __restrict__ Xt,
    unsigned short* __restrict__ Upart, float* __restrict__ sSp)
{
    __shared__ float raw[3][4096];           // 3 x 16 KB
    __shared__ unsigned short sAb[2][128 * SASTR];  // 2 x 9 KB

    const int t = threadIdx.x;
    const int w = t >> 6, lane = t & 63, q = lane >> 5, l31 = lane & 31;
    const int b = blockIdx.x;
    const int m  = b >> 3;
    const int nh = b & 1;
    const int h  = (b >> 1) & 3;
    const int row0 = m * 128, kbase = h * 2048;
    const int m0w = (w & 1) * 64, n0w = (w >> 1) * 64;

    // DMA roles: thread t covers raw bytes t*16 (row t>>3, float-col (t&7)*4),
    // round 2 covers +64 rows (+8 KB in LDS).
    const int srow = t >> 3, scol = (t & 7) * 4;
    const float* g0 = adj + (size_t)(row0 + srow) * 8192 + kbase + scol;
    const float* g1 = g0 + (size_t)64 * 8192;
    const int ldsW = w * 256;   // wave-uniform float offset (w*1024 B)

    // B base: per-lane direct global loads (L2/L3 resident Xt)
    const unsigned short* bB =
        Xt + (size_t)(nh * 256 + n0w + l31) * 8192 + kbase + q * 8;

    float rs0 = 0.f, rs1 = 0.f;
    f32x16_t acc[2][2];
#pragma unroll
    for (int a = 0; a < 2; ++a)
#pragma unroll
        for (int n = 0; n < 2; ++n)
#pragma unroll
            for (int e = 0; e < 16; ++e) acc[a][n][e] = 0.f;

    bf16x8_t bq[2][2];  // [ntile][kstep16]

#define DMA_CHUNK(C, SLOT) do {                                   \
        dma16(g0 + (size_t)(C) * 32, &raw[SLOT][ldsW]);           \
        dma16(g1 + (size_t)(C) * 32, &raw[SLOT][2048 + ldsW]);    \
    } while (0)

#define LOADB(C) do {                                                          \
        bq[0][0] = *(const bf16x8_t*)(bB + (size_t)(C) * 32);                  \
        bq[0][1] = *(const bf16x8_t*)(bB + (size_t)(C) * 32 + 16);             \
        bq[1][0] = *(const bf16x8_t*)(bB + (size_t)32 * 8192 + (size_t)(C) * 32);      \
        bq[1][1] = *(const bf16x8_t*)(bB + (size_t)32 * 8192 + (size_t)(C) * 32 + 16); \
    } while (0)

    auto convert = [&](int c, int buf) {
        const float* rp = &raw[c % 3][0];
        unsigned short* sp = &sAb[buf][0];
#pragma unroll
        for (int half = 0; half < 2; ++half) {
            const float4 v = *(const float4*)(rp + (size_t)t * 4 + half * 2048);
            float e0 = __expf(5.f * v.x);
            float e1 = __expf(5.f * v.y);
            float e2 = __expf(5.f * v.z);
            float e3 = __expf(5.f * v.w);
            const int gk = kbase + c * 32 + scol;
            const int grow = row0 + srow + half * 64;
            if (gk + 0 == grow) e0 = 0.f;
            if (gk + 1 == grow) e1 = 0.f;
            if (gk + 2 == grow) e2 = 0.f;
            if (gk + 3 == grow) e3 = 0.f;
            const float s4 = (e0 + e1) + (e2 + e3);
            if (half == 0) rs0 += s4; else rs1 += s4;
            uint2 p; p.x = pack2bf(e0, e1); p.y = pack2bf(e2, e3);
            *(uint2*)(sp + (size_t)(srow + half * 64) * SASTR + scol) = p;
        }
    };

    // ---- prologue: DMA chunks 0,1; convert chunk 0
    DMA_CHUNK(0, 0);
    DMA_CHUNK(1, 1);
    asm volatile("s_waitcnt vmcnt(2) lgkmcnt(0)\n\ts_barrier" ::: "memory");
    convert(0, 0);
    asm volatile("s_waitcnt lgkmcnt(0)\n\ts_barrier" ::: "memory");

    for (int c = 0; c < NCHV3; ++c) {
        const int buf = c & 1;
        // B for this chunk (issued before DMA so its waitcnt leaves DMA in flight)
        LOADB(c);
        // adj DMA 2 chunks ahead
        if (c + 2 < NCHV3) DMA_CHUNK(c + 2, (c + 2) % 3);
        // compute chunk c
        const unsigned short* sp = &sAb[buf][0];
#pragma unroll
        for (int ks = 0; ks < 2; ++ks) {
            bf16x8_t a0 = *(const bf16x8_t*)(sp + (size_t)(m0w + l31) * SASTR + ks * 16 + q * 8);
            bf16x8_t a1 = *(const bf16x8_t*)(sp + (size_t)(m0w + 32 + l31) * SASTR + ks * 16 + q * 8);
            acc[0][0] = MFMA32(a0, bq[0][ks], acc[0][0]);
            acc[1][0] = MFMA32(a1, bq[0][ks], acc[1][0]);
            acc[0][1] = MFMA32(a0, bq[1][ks], acc[0][1]);
            acc[1][1] = MFMA32(a1, bq[1][ks], acc[1][1]);
        }
        // barrier: wait only chunk c+1's data (leave c+2's 2 DMAs in flight)
        if (c + 2 < NCHV3)
            asm volatile("s_waitcnt vmcnt(2) lgkmcnt(0)\n\ts_barrier" ::: "memory");
        else
            asm volatile("s_waitcnt vmcnt(0) lgkmcnt(0)\n\ts_barrier" ::: "memory");
        // convert chunk c+1 into the other sA buffer
        if (c + 1 < NCHV3) convert(c + 1, buf ^ 1);
        asm volatile("s_waitcnt lgkmcnt(0)\n\ts_barrier" ::: "memory");
    }
#undef DMA_CHUNK
#undef LOADB

    // rowsum partials (8 stager threads per row; K-quarter h, only nh==0)
    rs0 += __shfl_xor(rs0, 1); rs0 += __shfl_xor(rs0, 2); rs0 += __shfl_xor(rs0, 4);
    rs1 += __shfl_xor(rs1, 1); rs1 += __shfl_xor(rs1, 2); rs1 += __shfl_xor(rs1, 4);
    if (((t & 7) == 0) && nh == 0) {
        sSp[h * 8192 + row0 + srow]      = rs0;
        sSp[h * 8192 + row0 + srow + 64] = rs1;
    }

    // store bf16 partials (C layout: col=lane&31, row=(reg&3)+8*(reg>>2)+4*q)
    unsigned short* up = Upart + (size_t)h * (8192 * 512) + (size_t)row0 * 512
                       + (nh * 256 + n0w + l31);
#pragma unroll
    for (int mt = 0; mt < 2; ++mt)
#pragma unroll
        for (int nt = 0; nt < 2; ++nt)
#pragma unroll
            for (int reg = 0; reg < 16; ++reg) {
                const int lrow = m0w + mt * 32 + (reg & 3) + 8 * (reg >> 2) + 4 * q;
                up[(size_t)lrow * 512 + nt * 32] = f2bf(acc[mt][nt][reg]);
            }
}

// ---------------------------------------------------------------------------
// finalize: sum 4 bf16 partials, normalize; agg -> XcatN[:,256:512],
// kagg -> Kcat[:,256:512]. grid = 8192, block = 256 (2 cols/thread).
// ---------------------------------------------------------------------------
__global__ __launch_bounds__(256) void finalize_agg(
    const unsigned* __restrict__ Upart, const float* __restrict__ sSp,
    unsigned* __restrict__ XcatN, unsigned* __restrict__ Kcat)
{
    const int row = blockIdx.x, t = threadIdx.x;
    const float inv = 1.f / (sSp[row] + sSp[8192 + row] + sSp[16384 + row] + sSp[24576 + row]);
    const unsigned* u = Upart + (size_t)row * 256 + t;
    float lo = 0.f, hi = 0.f;
#pragma unroll
    for (int hh = 0; hh < 4; ++hh) {
        const unsigned v = u[(size_t)hh * (8192 * 256)];
        lo += bflo(v); hi += bfhi(v);
    }
    const unsigned res = pack2bf(lo * inv, hi * inv);
    if (t < 128) XcatN[(size_t)row * 256 + 128 + t] = res;
    else         Kcat [(size_t)row * 256 + t]       = res;
}

// ---------------------------------------------------------------------------
// gemm_out: out[8192][256] f32 = tanh(A[8192][512]bf16 @ Wt[256][512]^T + c).
// grid = 256 (Mtile 32), block = 256 (4 waves). Padded LDS.
// ---------------------------------------------------------------------------
__global__ __launch_bounds__(256) void gemm_out(
    const unsigned short* __restrict__ A, const unsigned short* __restrict__ Wt,
    const float* __restrict__ cvec, float* __restrict__ out)
{
    __shared__ unsigned short sAm[32 * SASTR];
    __shared__ unsigned short sB[256 * SASTR];
    __shared__ float sBias[256];

    const int t = threadIdx.x, w = t >> 6, lane = t & 63;
    const int m_lo = lane & 15, quad = lane >> 4;
    const int row0 = blockIdx.x * 32;
    sBias[t] = cvec[t];

    f32x4_t acc[2][4];
#pragma unroll
    for (int a = 0; a < 2; ++a)
#pragma unroll
        for (int n = 0; n < 4; ++n)
#pragma unroll
            for (int e = 0; e < 4; ++e) acc[a][n][e] = 0.f;

    for (int ks = 0; ks < 16; ++ks) {
        const int k0 = ks * 32;
        __syncthreads();
        if (t < 128) {  // A tile 32x32
            bf16x8_t v = *(const bf16x8_t*)(A + (size_t)(row0 + (t >> 2)) * 512 + k0 + (t & 3) * 8);
            unsigned short* d = &sAm[(t >> 2) * SASTR + (t & 3) * 8];
            *(bf16x4_t*)d       = __builtin_shufflevector(v, v, 0, 1, 2, 3);
            *(bf16x4_t*)(d + 4) = __builtin_shufflevector(v, v, 4, 5, 6, 7);
        }
        {               // B tile 256x32, thread t stages n-row t
            const unsigned short* src = Wt + (size_t)t * 512 + k0;
            unsigned short* d = &sB[t * SASTR];
#pragma unroll
            for (int j = 0; j < 4; ++j) {
                bf16x8_t v = *(const bf16x8_t*)(src + j * 8);
                *(bf16x4_t*)(d + j * 8)     = __builtin_shufflevector(v, v, 0, 1, 2, 3);
                *(bf16x4_t*)(d + j * 8 + 4) = __builtin_shufflevector(v, v, 4, 5, 6, 7);
            }
        }
        __syncthreads();
        bf16x8_t a0, a1;
        {
            const unsigned short* p = &sAm[m_lo * SASTR + quad * 8];
            bf16x4_t lo = *(const bf16x4_t*)p, hi = *(const bf16x4_t*)(p + 4);
            a0 = __builtin_shufflevector(lo, hi, 0, 1, 2, 3, 4, 5, 6, 7);
            p += 16 * SASTR;
            lo = *(const bf16x4_t*)p; hi = *(const bf16x4_t*)(p + 4);
            a1 = __builtin_shufflevector(lo, hi, 0, 1, 2, 3, 4, 5, 6, 7);
        }
#pragma unroll
        for (int nt = 0; nt < 4; ++nt) {
            const unsigned short* p = &sB[(w * 64 + nt * 16 + m_lo) * SASTR + quad * 8];
            bf16x4_t lo = *(const bf16x4_t*)p, hi = *(const bf16x4_t*)(p + 4);
            bf16x8_t bb = __builtin_shufflevector(lo, hi, 0, 1, 2, 3, 4, 5, 6, 7);
            acc[0][nt] = MFMA16(a0, bb, acc[0][nt]);
            acc[1][nt] = MFMA16(a1, bb, acc[1][nt]);
        }
    }

#pragma unroll
    for (int mt = 0; mt < 2; ++mt)
#pragma unroll
        for (int nt = 0; nt < 4; ++nt) {
            const int col = w * 64 + nt * 16 + m_lo;
#pragma unroll
            for (int r = 0; r < 4; ++r) {
                const int row = row0 + mt * 16 + quad * 4 + r;
                out[(size_t)row * 256 + col] = tanhf(acc[mt][nt][r] + sBias[col]);
            }
        }
}

// ---------------------------------------------------------------------------
extern "C" void kernel_launch(void* const* d_in, const int* in_sizes, int n_in,
                              void* d_out, int out_size, void* d_ws, size_t ws_size,
                              hipStream_t stream) {
    const float* features = (const float*)d_in[0];
    const float* key      = (const float*)d_in[1];
    const float* adj      = (const float*)d_in[2];
    const float* W_d  = (const float*)d_in[3];
    const float* b_d  = (const float*)d_in[4];
    const float* W_o  = (const float*)d_in[5];
    const float* b_o  = (const float*)d_in[6];
    const float* W_a  = (const float*)d_in[7];
    const float* b_a  = (const float*)d_in[8];
    const float* W_ao = (const float*)d_in[9];
    const float* b_ao = (const float*)d_in[10];

    float* out1 = (float*)d_out;
    float* out2 = out1 + (size_t)8192 * 256;

    char* ws = (char*)d_ws;
    unsigned short* XcatN = (unsigned short*)(ws);                 // [8192][512] bf16
    unsigned short* Kcat  = (unsigned short*)(ws +  8388608);      // [8192][512] bf16
    unsigned short* Xt    = (unsigned short*)(ws + 16777216);      // [512][8192] bf16
    unsigned short* Upart = (unsigned short*)(ws + 25165824);      // [4][8192][512] bf16
    float*          sSp   = (float*)         (ws + 58720256);      // [4][8192] f32
    unsigned short* W1t   = (unsigned short*)(ws + 58851328);      // [256][512] bf16
    unsigned short* W2t   = (unsigned short*)(ws + 59113472);      // [256][512] bf16
    float*          c1    = (float*)         (ws + 59375616);      // [256]
    float*          c2    = (float*)         (ws + 59376640);      // [256]

    dim3 blk(256);
    transpose_f32_bf16<<<dim3(256, 8), blk, 0, stream>>>(features, Xt, 8192, 256);
    transpose_f32_bf16<<<dim3(256, 8), blk, 0, stream>>>(key, Xt + (size_t)256 * 8192, 8192, 256);
    pack_half<<<4096, blk, 0, stream>>>(features, (unsigned*)XcatN);
    pack_half<<<4096, blk, 0, stream>>>(key, (unsigned*)Kcat);
    compose1<<<512, blk, 0, stream>>>(W_d, W_o, W1t);
    compose2<<<512, blk, 0, stream>>>(W_a, W_ao, W2t);
    biasC<<<1, blk, 0, stream>>>(b_d, b_o, b_a, b_ao, W_o, W_ao, c1, c2);

    exp_gemm<<<512, dim3(512), 0, stream>>>(adj, Xt, Upart, sSp);
    finalize_agg<<<8192, blk, 0, stream>>>((const unsigned*)Upart, sSp,
                                           (unsigned*)XcatN, (unsigned*)Kcat);

    gemm_out<<<256, blk, 0, stream>>>(XcatN, W1t, c1, out1);
    gemm_out<<<256, blk, 0, stream>>>(Kcat,  W2t, c2, out2);
}